// Round 4
// baseline (3894.525 us; speedup 1.0000x reference)
//
#include <hip/hip_runtime.h>
#include <math.h>

// NMSLoss3: sequential greedy-NMS pull/push loss.
// B=2, N=2048 proposals, G=64 gt boxes. Output: 2 floats [push/B, pull/B].
//
// One wavefront per batch (no barriers in the serial loop; all cross-lane
// traffic via __shfl). Lane L owns slots j = k*64 + L, k in [0,32), with a
// 32-bit per-lane alive mask.
//
// R4 changes vs R3:
//  - software-pipelined selection: step s+1's u64 argmax reduce is fused
//    into the SAME 6-hop __shfl_xor loop as step s's psum/packed reduce
//    (3 independent shuffles per hop -> one cross-lane latency chain per
//    step instead of two).
// Carried from earlier rounds: packed u64 (score_bits || ~j) selection
// cache per lane (rebuilt only when its max dies), 4-way batched ctz
// overlap scan, hipMemsetAsync output zeroing.

#define NMS_THR 0.5f
#define EPS_F 1e-6f

__device__ __forceinline__ unsigned long long pack_sj(float s, int j) {
    // s > 0 assumed (scores in [0.05, 1.0]); larger s => larger bits.
    // ~j in low word => on equal score, SMALLER j wins the max
    // (matches jnp.argmax first-index tie-break).
    return ((unsigned long long)__float_as_uint(s) << 32) |
           (unsigned long long)(0xffffffffu - (unsigned)j);
}

__global__ __launch_bounds__(64, 1) void nms_loss_kernel(
    const int* __restrict__ gt_inds,      // [B, N]
    const float* __restrict__ gt_bboxes,  // [B, G, 4]
    const float* __restrict__ proposals,  // [B, N, 5]
    float* __restrict__ out,              // [2]
    int N, int G, float inv_B)
{
    const int b    = blockIdx.x;
    const int lane = threadIdx.x;   // 0..63

    __shared__ float4 boxes[2048];
    __shared__ float2 sg[2048];        // (score, __int_as_float(gi))
    __shared__ float  gtiou[64 * 64];

    const int*   gi_b   = gt_inds   + (size_t)b * N;
    const float* prop_b = proposals + (size_t)b * N * 5;
    const float* gtb    = gt_bboxes + (size_t)b * G * 4;

    const int SLOTS = N >> 6;   // 32

    // ---- preload proposals into LDS + build per-lane packed max cache ----
    unsigned long long cache = 0ULL;   // 0 == empty (any real score packs > 0)
    for (int k = 0; k < SLOTS; ++k) {
        int j = k * 64 + lane;
        const float* p = prop_b + j * 5;
        float x1 = p[0], y1 = p[1], x2 = p[2], y2 = p[3], s = p[4];
        boxes[j] = make_float4(x1, y1, x2, y2);
        sg[j]    = make_float2(s, __int_as_float(gi_b[j]));
        unsigned long long c = pack_sj(s, j);
        if (c > cache) cache = c;
    }

    // ---- gt boxes in registers (lane l holds gt box l), gt_iou table ----
    // Reference order: iou[row][col] with denom (area_row + area_col) - inter.
    float4 gb = make_float4(0.f, 0.f, 0.f, 0.f);
    if (lane < G) {
        gb.x = gtb[lane * 4 + 0];
        gb.y = gtb[lane * 4 + 1];
        gb.z = gtb[lane * 4 + 2];
        gb.w = gtb[lane * 4 + 3];
    }
    float area_l = (gb.z - gb.x) * (gb.w - gb.y);
    for (int c = 0; c < G; ++c) {
        float cx1 = __shfl(gb.x, c), cy1 = __shfl(gb.y, c);
        float cx2 = __shfl(gb.z, c), cy2 = __shfl(gb.w, c);
        float area_c = (cx2 - cx1) * (cy2 - cy1);
        float ltx = fmaxf(gb.x, cx1), lty = fmaxf(gb.y, cy1);
        float rbx = fminf(gb.z, cx2), rby = fminf(gb.w, cy2);
        float w = fmaxf(rbx - ltx, 0.0f), h = fmaxf(rby - lty, 0.0f);
        float inter = w * h;
        if (lane < G)
            gtiou[lane * 64 + c] = inter / (area_l + area_c - inter + 1e-12f);
    }
    __syncthreads();   // single wave: cheap; makes LDS writes visible

    // ---- serial greedy NMS ----
    unsigned int alive = 0xffffffffu;   // bit k <=> j = k*64+lane alive
    int   alive_count = N;
    int   rec_reg = -1;                 // rec[lane] (lane == gt index)
    float pull_s = 0.0f, push_s = 0.0f, pull_c = 0.0f, push_c = 0.0f;

    // prologue: selection for step 0
    unsigned long long best = cache;
    for (int off = 32; off; off >>= 1) {
        unsigned long long o = __shfl_xor(best, off);
        if (o > best) best = o;
    }

    for (int step = 0; step < N && alive_count > 0; ++step) {
        const int   i  = (int)(0xffffffffu - (unsigned)(best & 0xffffffffu));
        const float si = __uint_as_float((unsigned)(best >> 32));

        const int g = __float_as_int(sg[i].y);
        const int rec_g = __shfl(rec_reg, g);
        const bool has_rec = rec_g >= 0;

        // kill i (before the overlap scan => scan sees alive2)
        if (lane == (i & 63)) alive &= ~(1u << (i >> 6));
        alive_count -= 1;
        const bool remaining = alive_count > 0;

        const float4 bi = boxes[i];
        const float area_i = (bi.z - bi.x) * (bi.w - bi.y);

        if (has_rec) {
            pull_c += 1.0f;
            if (remaining) {
                float4 br = boxes[rec_g];
                float area_r = (br.z - br.x) * (br.w - br.y);
                float ltx = fmaxf(br.x, bi.x), lty = fmaxf(br.y, bi.y);
                float rbx = fminf(br.z, bi.z), rby = fminf(br.w, bi.w);
                float w = fmaxf(rbx - ltx, 0.0f), h = fmaxf(rby - lty, 0.0f);
                float inter = w * h;
                float iou = inter / (area_r + area_i - inter + 1e-12f);
                float msi = fmaxf(iou, EPS_F);
                pull_s += -logf(1.0f - NMS_THR + msi) * si;
            }
        } else {
            if (lane == g) rec_reg = i;
        }

        // -- push loss + overlap kill over alive (i already removed) --
        float psum = 0.0f;
        int   pcnt = 0, killed = 0;
        unsigned int newalive = alive;
        const float* __restrict__ gtrow = &gtiou[g * 64];

        auto process = [&](int k, const float4& bx, bool valid) {
            float area_j = (bx.z - bx.x) * (bx.w - bx.y);
            float ltx = fmaxf(bi.x, bx.x), lty = fmaxf(bi.y, bx.y);
            float rbx = fminf(bi.z, bx.z), rby = fminf(bi.w, bx.w);
            float w = fmaxf(rbx - ltx, 0.0f), h = fmaxf(rby - lty, 0.0f);
            float inter = w * h;
            float iou = inter / (area_i + area_j - inter + 1e-12f);
            if (valid && iou > NMS_THR) {
                killed++;
                newalive &= ~(1u << k);
                float2 sgj = sg[k * 64 + lane];
                int gj = __float_as_int(sgj.y);
                if (gj != g && iou > gtrow[gj]) {
                    pcnt++;
                    psum += (-logf(1.0f + NMS_THR - iou) - logf(sgj.x)) * sgj.x;
                }
            }
        };

        // 4-way batched ctz scan: 4 independent ds_read_b128 in flight;
        // invalid tail slots duplicate k0 and are masked by the valid flag.
        unsigned int m = alive;
        while (m) {
            int k0 = __builtin_ctz(m); m &= m - 1;
            bool v1 = m != 0; int k1 = k0;
            if (v1) { k1 = __builtin_ctz(m); m &= m - 1; }
            bool v2 = m != 0; int k2 = k0;
            if (v2) { k2 = __builtin_ctz(m); m &= m - 1; }
            bool v3 = m != 0; int k3 = k0;
            if (v3) { k3 = __builtin_ctz(m); m &= m - 1; }

            float4 b0 = boxes[k0 * 64 + lane];
            float4 b1 = boxes[k1 * 64 + lane];
            float4 b2 = boxes[k2 * 64 + lane];
            float4 b3 = boxes[k3 * 64 + lane];

            process(k0, b0, true);
            process(k1, b1, v1);
            process(k2, b2, v2);
            process(k3, b3, v3);
        }
        alive = newalive;

        // -- rebuild this lane's cache only if its cached max died --
        // (must precede the fused reduce: next selection sees post-kill state)
        if (cache != 0ULL) {
            int cj = (int)(0xffffffffu - (unsigned)(cache & 0xffffffffu));
            if (!((alive >> (cj >> 6)) & 1u)) {
                cache = 0ULL;
                unsigned int mm = alive;
                while (mm) {
                    int k = __builtin_ctz(mm); mm &= mm - 1;
                    int j = k * 64 + lane;
                    unsigned long long c = pack_sj(sg[j].x, j);
                    if (c > cache) cache = c;
                }
            }
        }

        // -- fused 6-hop reduce: next-step selection (u64 max) + psum (f32)
        //    + packed killed/pcnt (i32). Three independent shuffles share
        //    one latency chain.
        unsigned long long nb = cache;
        float ps = psum;
        int   pk = (killed << 16) | pcnt;   // sums <= 2048 each, no overflow
        for (int off = 32; off; off >>= 1) {
            unsigned long long ob = __shfl_xor(nb, off);
            float of = __shfl_xor(ps, off);
            int   oi = __shfl_xor(pk, off);
            if (ob > nb) nb = ob;
            ps += of;
            pk += oi;
        }
        best = nb;
        const int killed_t = pk >> 16;
        const int pcnt_t   = pk & 0xffff;

        alive_count -= killed_t;
        if (pcnt_t > 0) push_s += ps / (float)pcnt_t;
        push_c += (float)pcnt_t;
    }

    // finalize: batch loss, averaged over B (PUSH_W = PULL_W = 1)
    float push_norm = push_s / (push_c + EPS_F);
    float pull_norm = pull_s / (pull_c + EPS_F);
    if (lane == 0) {
        atomicAdd(&out[0], push_norm * inv_B);
        atomicAdd(&out[1], pull_norm * inv_B);
    }
}

extern "C" void kernel_launch(void* const* d_in, const int* in_sizes, int n_in,
                              void* d_out, int out_size, void* d_ws, size_t ws_size,
                              hipStream_t stream) {
    // inputs (setup_inputs order): gt_inds[B,N] i32, anchor_gt_inds[B,N] i32,
    // gt_bboxes[B,G,4] f32, proposal_list[B,N,5] f32
    const int B = 2;
    const int N = in_sizes[1] / B;          // 2048
    const int G = in_sizes[2] / (B * 4);    // 64

    const int*   anchor_gt = (const int*)d_in[1];
    const float* gt_bboxes = (const float*)d_in[2];
    const float* proposals = (const float*)d_in[3];
    float* out = (float*)d_out;

    hipMemsetAsync(out, 0, 2 * sizeof(float), stream);
    nms_loss_kernel<<<B, 64, 0, stream>>>(anchor_gt, gt_bboxes, proposals,
                                          out, N, G, 1.0f / (float)B);
}

// Round 10
// 3003.222 us; speedup vs baseline: 1.2968x; 1.2968x over previous
//
#include <hip/hip_runtime.h>
#include <math.h>

// NMSLoss3: sequential greedy-NMS pull/push loss.
// B=2, N=2048 proposals, G=64 gt boxes. Output: 2 floats [push/B, pull/B].
//
// R10 = R9 + register-resident scores/gt-inds (R4 measured baseline: 3894us,
// bit-exact, VALUBusy=0.09% => pure latency chain; R5-R9 never ran):
//  - pre-sort by descending score (in-LDS bitonic, u64 keys): selection ==
//    first alive in sorted order, found for free during the kill scan.
//  - replicated alive mask aw[32] (u64, uniform across lanes) + __ballot
//    bookkeeping: killed/pcnt are uniform popcounts; psum reduce runs only
//    on steps that produced eligible kills.
//  - boxes, areas, scores, gt-inds ALL REGISTER-RESIDENT per lane
//    (box_reg/area_reg/sc_reg/gi_reg[32], static unrolled indexing):
//    the kill scan issues ZERO LDS operations.
//  - next-selection prefetch: next_p's box/score LDS broadcast reads are
//    issued mid-scan and overlap the remaining scan words.
//  - rec boxes live on lane g (5 regs), fetched via 5 independent __shfl.
//  - NOT done (exactness): multiply-form threshold test can flip decisions
//    within ~2^-25 of THR (expected ~0.25 flips / 8.4M cmps). IEEE div kept.
// All IoU arithmetic keeps the exact operand order of the R4 bit-exact
// kernel (IEEE div, (area_a + area_b - inter) + 1e-12, same gating).

#define NMS_THR 0.5f
#define EPS_F 1e-6f
#define NPAD 2048          // power-of-2 capacity (N == 2048 here)
#define NWORDS 32          // NPAD / 64

__global__ __launch_bounds__(64, 1) void nms_loss_kernel(
    const int* __restrict__ gt_inds,      // [B, N]
    const float* __restrict__ gt_bboxes,  // [B, G, 4]
    const float* __restrict__ proposals,  // [B, N, 5]
    float* __restrict__ out,              // [2]
    int N, int G, float inv_B)
{
    const int b    = blockIdx.x;
    const int lane = threadIdx.x;   // 0..63

    __shared__ unsigned long long skey[NPAD];   // 16KB; becomes sgg_s after sort
    __shared__ float4 boxes_s[NPAD];            // 32KB (sorted boxes)
    __shared__ float  gtiou[64 * 64];           // 16KB
    float2* sgg_s = reinterpret_cast<float2*>(skey);   // (score, gi bits), sorted

    const int*   gi_b   = gt_inds   + (size_t)b * N;
    const float* prop_b = proposals + (size_t)b * N * 5;
    const float* gtb    = gt_bboxes + (size_t)b * G * 4;

    // ---- build sort keys: ascending sort of ~(score_bits<<32 | ~j)
    //      => descending score, tie -> smaller original j first ----
    for (int j = lane; j < NPAD; j += 64) {
        unsigned long long key;
        if (j < N) {
            float s = prop_b[(size_t)j * 5 + 4];   // scores in (0,1] => bits order-isomorphic
            key = ~(((unsigned long long)__float_as_uint(s) << 32)
                    | (unsigned long long)(0xffffffffu - (unsigned)j));
        } else {
            key = ~0ULL;                            // pads sort to the end
        }
        skey[j] = key;
    }
    __syncthreads();

    // ---- bitonic sort (ascending), single wave, 2048 elements ----
    for (int k = 2; k <= NPAD; k <<= 1) {
        for (int jj = k >> 1; jj > 0; jj >>= 1) {
            for (int t = lane; t < NPAD; t += 64) {
                int l = t ^ jj;
                if (l > t) {
                    unsigned long long a = skey[t], c = skey[l];
                    bool up = ((t & k) == 0);
                    if ((a > c) == up) { skey[t] = c; skey[l] = a; }
                }
            }
            __syncthreads();
        }
    }

    // ---- stage sorted original indices into registers, then overwrite
    //      skey storage with the gathered (score, gi) pairs ----
    // low 32 bits of key == original index j (since ~(0xffffffff-j) == j)
    unsigned idxs[NWORDS];
    #pragma unroll
    for (int w = 0; w < NWORDS; ++w) idxs[w] = (unsigned)skey[w * 64 + lane];
    __syncthreads();   // all key reads done before sgg_s overwrites skey

    #pragma unroll
    for (int w = 0; w < NWORDS; ++w) {
        int sp = w * 64 + lane;
        if (sp < N) {
            unsigned idx = idxs[w];
            const float* pr = prop_b + (size_t)idx * 5;
            boxes_s[sp] = make_float4(pr[0], pr[1], pr[2], pr[3]);
            sgg_s[sp]   = make_float2(pr[4], __int_as_float(gi_b[idx]));
        } else {
            boxes_s[sp] = make_float4(0.f, 0.f, 0.f, 0.f);
            sgg_s[sp]   = make_float2(1.0f, __int_as_float(0));
        }
    }

    // ---- gt iou table: gtiou[row*64+col], denom (area_row+area_col)-inter ----
    float4 gb = make_float4(0.f, 0.f, 0.f, 0.f);
    if (lane < G) {
        gb.x = gtb[lane * 4 + 0];
        gb.y = gtb[lane * 4 + 1];
        gb.z = gtb[lane * 4 + 2];
        gb.w = gtb[lane * 4 + 3];
    }
    float area_l = (gb.z - gb.x) * (gb.w - gb.y);
    for (int c = 0; c < G; ++c) {
        float cx1 = __shfl(gb.x, c), cy1 = __shfl(gb.y, c);
        float cx2 = __shfl(gb.z, c), cy2 = __shfl(gb.w, c);
        float area_c = (cx2 - cx1) * (cy2 - cy1);
        float ltx = fmaxf(gb.x, cx1), lty = fmaxf(gb.y, cy1);
        float rbx = fminf(gb.z, cx2), rby = fminf(gb.w, cy2);
        float w = fmaxf(rbx - ltx, 0.0f), h = fmaxf(rby - lty, 0.0f);
        float inter = w * h;
        if (lane < G)
            gtiou[lane * 64 + c] = inter / (area_l + area_c - inter + 1e-12f);
    }
    __syncthreads();

    // ---- register-resident per-lane data (static unrolled => VGPRs) ----
    float4 box_reg[NWORDS];
    float  area_reg[NWORDS];
    float  sc_reg[NWORDS];
    int    gi_reg[NWORDS];
    #pragma unroll
    for (int r = 0; r < NWORDS; ++r) {
        box_reg[r]  = boxes_s[r * 64 + lane];
        area_reg[r] = (box_reg[r].z - box_reg[r].x) * (box_reg[r].w - box_reg[r].y);
        float2 sgj  = sgg_s[r * 64 + lane];
        sc_reg[r]   = sgj.x;
        gi_reg[r]   = __float_as_int(sgj.y);
    }

    // ---- replicated alive mask over sorted positions ----
    unsigned long long aw[NWORDS];
    #pragma unroll
    for (int r = 0; r < NWORDS; ++r) {
        long base = (long)r * 64;
        aw[r] = (base + 64 <= N) ? ~0ULL
              : ((base >= N) ? 0ULL : ((~0ULL) >> (64 - (int)(N - base))));
    }

    int   alive_count = N;
    int   rec_reg = -1;          // lane g holds sorted position of rec[g] ...
    float rec_x = 0.f, rec_y = 0.f, rec_z = 0.f, rec_w = 0.f, rec_a = 0.f;
    //    ... and its box coords + area (bits identical to boxes_s[rec])
    float pull_s = 0.0f, push_s = 0.0f, pull_c = 0.0f, push_c = 0.0f;

    // first selection = sorted position 0 (highest score); clear its bit and
    // prefetch its data.
    int p = (N > 0) ? 0 : -1;
    float4 nbi = make_float4(0.f, 0.f, 0.f, 0.f);
    float2 nsm = make_float2(1.0f, __int_as_float(0));
    if (p == 0) {
        aw[0] &= ~1ULL;
        nbi = boxes_s[0];
        nsm = sgg_s[0];
    }

    for (int step = 0; step < N && p >= 0; ++step) {
        const float4 bi = nbi;                   // prefetched broadcast data
        const float2 sm = nsm;
        const float  si = sm.x;
        const int    g  = __float_as_int(sm.y);
        const float  area_i = (bi.z - bi.x) * (bi.w - bi.y);

        const int  rec_g   = __shfl(rec_reg, g);
        const bool has_rec = rec_g >= 0;

        alive_count -= 1;                        // i removed (bit pre-cleared)
        const bool remaining = alive_count > 0;

        if (has_rec) {
            pull_c += 1.0f;
            if (remaining) {
                // rec box from lane g's registers (5 independent shuffles)
                float brx = __shfl(rec_x, g), bry = __shfl(rec_y, g);
                float brz = __shfl(rec_z, g), brw = __shfl(rec_w, g);
                float area_r = __shfl(rec_a, g);
                float ltx = fmaxf(brx, bi.x), lty = fmaxf(bry, bi.y);
                float rbx = fminf(brz, bi.z), rby = fminf(brw, bi.w);
                float w = fmaxf(rbx - ltx, 0.0f), h = fmaxf(rby - lty, 0.0f);
                float inter = w * h;
                float iou = inter / (area_r + area_i - inter + 1e-12f);
                float msi = fmaxf(iou, EPS_F);
                pull_s += -logf(1.0f - NMS_THR + msi) * si;
            }
        } else {
            if (lane == g) {
                rec_reg = p;
                rec_x = bi.x; rec_y = bi.y; rec_z = bi.z; rec_w = bi.w;
                rec_a = area_i;
            }
        }

        // -- kill scan (fully register-resident; zero LDS ops) --
        float psum = 0.0f;
        int   pcnt = 0, killed = 0;
        int   next_p = -1;
        const float* __restrict__ gtrow = &gtiou[g * 64];

        #pragma unroll
        for (int r = 0; r < NWORDS; ++r) {
            if (aw[r] != 0ULL) {                  // uniform; front words die
                const float4 bx = box_reg[r];
                float ltx = fmaxf(bi.x, bx.x), lty = fmaxf(bi.y, bx.y);
                float rbx = fminf(bi.z, bx.z), rby = fminf(bi.w, bx.w);
                float w = fmaxf(rbx - ltx, 0.0f), h = fmaxf(rby - lty, 0.0f);
                float inter = w * h;
                float iou = inter / (area_i + area_reg[r] - inter + 1e-12f);
                unsigned long long K = aw[r] & __ballot(iou > NMS_THR);
                if (K) {
                    aw[r] &= ~K;
                    killed += __popcll(K);
                    int gj = gi_reg[r];
                    unsigned long long E =
                        K & __ballot((gj != g) && (iou > gtrow[gj]));
                    if (E) {
                        pcnt += __popcll(E);
                        bool elig = (E >> lane) & 1ULL;
                        float sj = sc_reg[r];
                        float pv = (-logf(1.0f + NMS_THR - iou) - logf(sj))
                                   * sj;
                        psum += elig ? pv : 0.0f;
                    }
                }
                // first survivor in sorted order = next selection: clear its
                // bit and prefetch its data NOW (overlaps remaining words).
                // Kills in later words r' > r cannot touch position next_p.
                if (next_p < 0 && aw[r]) {
                    int bp = __builtin_ctzll(aw[r]);
                    next_p = r * 64 + bp;
                    aw[r] &= ~(1ULL << bp);
                    nbi = boxes_s[next_p];
                    nsm = sgg_s[next_p];
                }
            }
        }

        alive_count -= killed;
        if (pcnt > 0) {                           // rare: reduce only then
            float ps = psum;
            for (int off = 32; off; off >>= 1) ps += __shfl_xor(ps, off);
            push_s += ps / (float)pcnt;
            push_c += (float)pcnt;
        }
        p = next_p;
    }

    // finalize: batch loss, averaged over B (PUSH_W = PULL_W = 1)
    float push_norm = push_s / (push_c + EPS_F);
    float pull_norm = pull_s / (pull_c + EPS_F);
    if (lane == 0) {
        atomicAdd(&out[0], push_norm * inv_B);
        atomicAdd(&out[1], pull_norm * inv_B);
    }
}

extern "C" void kernel_launch(void* const* d_in, const int* in_sizes, int n_in,
                              void* d_out, int out_size, void* d_ws, size_t ws_size,
                              hipStream_t stream) {
    // inputs (setup_inputs order): gt_inds[B,N] i32, anchor_gt_inds[B,N] i32,
    // gt_bboxes[B,G,4] f32, proposal_list[B,N,5] f32
    const int B = 2;
    const int N = in_sizes[1] / B;          // 2048
    const int G = in_sizes[2] / (B * 4);    // 64

    const int*   anchor_gt = (const int*)d_in[1];
    const float* gt_bboxes = (const float*)d_in[2];
    const float* proposals = (const float*)d_in[3];
    float* out = (float*)d_out;

    hipMemsetAsync(out, 0, 2 * sizeof(float), stream);
    nms_loss_kernel<<<B, 64, 0, stream>>>(anchor_gt, gt_bboxes, proposals,
                                          out, N, G, 1.0f / (float)B);
}